// Round 1
// baseline (3249.839 us; speedup 1.0000x reference)
//
#include <hip/hip_runtime.h>
#include <hip/hip_bf16.h>
#include <stdint.h>

// TiedEmbeddingLinear: out[8192, 32768] = x[8192,4096] . W^T,
// W[v,d] dequantized NF4 from q_weight[32768,2048] (byte-in-int32, 2 nibbles),
// absmax applied in epilogue (linear in each output column).

#define M_DIM 8192
#define N_DIM 32768
#define K_DIM 4096
#define P_DIM 2048

#define BM 128
#define BN 128
#define BK 64
#define LDS_STRIDE 72   // 64 + 8 pad: 144B rows -> 36-dword stride -> 2-way bank alias (free)

typedef __attribute__((ext_vector_type(8))) short short8;
typedef __attribute__((ext_vector_type(4))) float f32x4;

__device__ __forceinline__ ushort f2bf(float f) {
    union { __hip_bfloat16 b; ushort u; } cv;
    cv.b = __float2bfloat16(f);
    return cv.u;
}

__global__ __launch_bounds__(256) void nf4_gemm(
    const float* __restrict__ x, const int* __restrict__ qw,
    const float* __restrict__ absmax, const float* __restrict__ cb,
    float* __restrict__ out)
{
    __shared__ ushort As[BM * LDS_STRIDE];   // 18432 B
    __shared__ ushort Bs[BN * LDS_STRIDE];   // 18432 B
    __shared__ uint32_t lut[256];            // packed bf16 pair per byte

    const int tid = threadIdx.x;
    const int gm0 = blockIdx.x * BM;   // m-tile (fast dim -> concurrent blocks share q panel)
    const int gn0 = blockIdx.y * BN;

    // Build dequant LUT: low 16 bits = even d (HIGH nibble), high 16 = odd d (LOW nibble)
    {
        const int hi = (tid >> 4) & 15;
        const int lo = tid & 15;
        const uint32_t h = f2bf(cb[hi]);
        const uint32_t l = f2bf(cb[lo]);
        lut[tid] = h | (l << 16);
    }
    __syncthreads();

    const int lane = tid & 63;
    const int wv = tid >> 6;        // wave 0..3
    const int wr = wv >> 1;         // wave row (2)
    const int wc = wv & 1;          // wave col (2)
    const int lr = lane & 15;       // fragment row/col
    const int g  = lane >> 4;       // k-group 0..3

    f32x4 acc[4][4] = {};

    // staging decomposition
    const int ac = tid & 15;        // float4 slot within a 64-float row
    const int ar = tid >> 4;        // row base 0..15 (8 passes of 16 rows)
    const int bn = tid >> 1;        // B row 0..127
    const int bh = tid & 1;         // which half of the 32 ints

    const float* xg = x + (size_t)gm0 * K_DIM + ac * 4;
    const int*   qg = qw + (size_t)(gn0 + bn) * P_DIM + bh * 16;

    for (int kt = 0; kt < K_DIM / BK; ++kt) {
        // ---- stage A: 128x64 fp32 -> bf16 ----
        {
            const float* xk = xg + kt * BK;
            #pragma unroll
            for (int p = 0; p < 8; ++p) {
                const int row = ar + p * 16;
                const float4 v = *(const float4*)(xk + (size_t)row * K_DIM);
                ushort4 w4;
                w4.x = f2bf(v.x); w4.y = f2bf(v.y);
                w4.z = f2bf(v.z); w4.w = f2bf(v.w);
                *(ushort4*)(&As[row * LDS_STRIDE + ac * 4]) = w4;
            }
        }
        // ---- stage B: 128 rows x 32 ints -> 64 bf16/row via LUT ----
        {
            const int* qk = qg + kt * 32;
            const int4 q0 = *(const int4*)(qk + 0);
            const int4 q1 = *(const int4*)(qk + 4);
            const int4 q2 = *(const int4*)(qk + 8);
            const int4 q3 = *(const int4*)(qk + 12);
            uint4 w0, w1, w2, w3;
            w0.x = lut[q0.x & 255]; w0.y = lut[q0.y & 255];
            w0.z = lut[q0.z & 255]; w0.w = lut[q0.w & 255];
            w1.x = lut[q1.x & 255]; w1.y = lut[q1.y & 255];
            w1.z = lut[q1.z & 255]; w1.w = lut[q1.w & 255];
            w2.x = lut[q2.x & 255]; w2.y = lut[q2.y & 255];
            w2.z = lut[q2.z & 255]; w2.w = lut[q2.w & 255];
            w3.x = lut[q3.x & 255]; w3.y = lut[q3.y & 255];
            w3.z = lut[q3.z & 255]; w3.w = lut[q3.w & 255];
            uint32_t* bp = (uint32_t*)(&Bs[bn * LDS_STRIDE + bh * 32]);
            *(uint4*)(bp + 0)  = w0;
            *(uint4*)(bp + 4)  = w1;
            *(uint4*)(bp + 8)  = w2;
            *(uint4*)(bp + 12) = w3;
        }
        __syncthreads();

        // ---- compute: 2 k-substeps x 16 MFMA ----
        #pragma unroll
        for (int kk = 0; kk < BK; kk += 32) {
            short8 af[4], bf[4];
            #pragma unroll
            for (int m = 0; m < 4; ++m)
                af[m] = *(const short8*)(&As[(wr * 64 + m * 16 + lr) * LDS_STRIDE + kk + g * 8]);
            #pragma unroll
            for (int n = 0; n < 4; ++n)
                bf[n] = *(const short8*)(&Bs[(wc * 64 + n * 16 + lr) * LDS_STRIDE + kk + g * 8]);
            #pragma unroll
            for (int m = 0; m < 4; ++m)
                #pragma unroll
                for (int n = 0; n < 4; ++n)
                    acc[m][n] = __builtin_amdgcn_mfma_f32_16x16x32_bf16(af[m], bf[n], acc[m][n], 0, 0, 0);
        }
        __syncthreads();
    }

    // ---- epilogue: scale by absmax[col], store fp32 ----
    float am[4];
    #pragma unroll
    for (int n = 0; n < 4; ++n)
        am[n] = absmax[gn0 + wc * 64 + n * 16 + lr];

    #pragma unroll
    for (int m = 0; m < 4; ++m) {
        const int row = gm0 + wr * 64 + m * 16 + g * 4;
        #pragma unroll
        for (int n = 0; n < 4; ++n) {
            const int col = gn0 + wc * 64 + n * 16 + lr;
            #pragma unroll
            for (int r = 0; r < 4; ++r) {
                out[(size_t)(row + r) * N_DIM + col] = acc[m][n][r] * am[n];
            }
        }
    }
}

extern "C" void kernel_launch(void* const* d_in, const int* in_sizes, int n_in,
                              void* d_out, int out_size, void* d_ws, size_t ws_size,
                              hipStream_t stream) {
    const float* x      = (const float*)d_in[0];
    const int*   qw     = (const int*)d_in[1];
    const float* absmax = (const float*)d_in[2];
    const float* cb     = (const float*)d_in[3];
    float* out = (float*)d_out;

    dim3 grid(M_DIM / BM, N_DIM / BN);   // (64, 256), m fast
    nf4_gemm<<<grid, dim3(256), 0, stream>>>(x, qw, absmax, cb, out);
}